// Round 11
// baseline (250.754 us; speedup 1.0000x reference)
//
#include <hip/hip_runtime.h>
#include <cstdint>
#include <cstddef>

typedef __attribute__((ext_vector_type(8))) short bf16x8;    // 8 bf16 = 4 VGPRs
typedef __attribute__((ext_vector_type(4))) float f32x4;
typedef __attribute__((ext_vector_type(16))) float f32x16;

#define MFMA16(a, b, c) __builtin_amdgcn_mfma_f32_16x16x32_bf16((a), (b), (c), 0, 0, 0)
#define MFMA32(a, b, c) __builtin_amdgcn_mfma_f32_32x32x16_bf16((a), (b), (c), 0, 0, 0)

constexpr int Bz = 4, S = 2048, E = 1024, H = 16, Dh = 64;
constexpr size_t BSE = (size_t)Bz * S * E;   // 8388608

__device__ __forceinline__ unsigned short f2bf(float f) {
    uint32_t u = __builtin_bit_cast(uint32_t, f);
    u += 0x7FFFu + ((u >> 16) & 1u);   // round-to-nearest-even
    return (unsigned short)(u >> 16);
}

__device__ __forceinline__ float exp2_fast(float x) {
#if __has_builtin(__builtin_amdgcn_exp2f)
    return __builtin_amdgcn_exp2f(x);
#else
    return exp2f(x);
#endif
}

// pack two floats to packed bf16 (round-half-up): 2 adds + 1 v_perm
__device__ __forceinline__ uint32_t pack_bf16(float a, float b) {
    uint32_t ua = __builtin_bit_cast(uint32_t, a) + 0x8000u;
    uint32_t ub = __builtin_bit_cast(uint32_t, b) + 0x8000u;
#if __has_builtin(__builtin_amdgcn_perm)
    return __builtin_amdgcn_perm(ub, ua, 0x07060302u);   // {ub.hi16, ua.hi16}
#else
    return (ua >> 16) | (ub & 0xFFFF0000u);
#endif
}

// async global -> LDS, 16 B per lane; LDS dst = wave-uniform base + lane*16
__device__ __forceinline__ void gload16(const unsigned short* g, unsigned short* l) {
    __builtin_amdgcn_global_load_lds((const __attribute__((address_space(1))) void*)g,
                                     (__attribute__((address_space(3))) void*)l, 16, 0, 0);
}

// ---------------- K convert + V transpose + W convert, one pass ----------------
// (convert_kernel fused: 2048 blocks x 256 threads x 2 floats = E*E exactly)
__global__ __launch_bounds__(256) void prep_kv(const float* __restrict__ k,
                                               const float* __restrict__ v,
                                               const float* __restrict__ w,
                                               unsigned short* __restrict__ kb,
                                               unsigned short* __restrict__ vt,
                                               unsigned short* __restrict__ wb) {
    __shared__ unsigned short tile[64][65];
    const int b = blockIdx.z, h = blockIdx.y, s0 = blockIdx.x * 64;
    const int r = threadIdx.x >> 2, cb = (threadIdx.x & 3) * 16;
    const size_t off = (size_t)(b * S + s0 + r) * E + h * Dh + cb;

    {   // K: convert in place (coalesced b128 out), float4 loads
        const float* src = k + off;
        uint32_t o[8];
#pragma unroll
        for (int j = 0; j < 4; ++j) {
            float4 f = *(const float4*)(src + 4 * j);
            o[2 * j + 0] = pack_bf16(f.x, f.y);
            o[2 * j + 1] = pack_bf16(f.z, f.w);
        }
        unsigned short* dst = kb + off;
        *(uint4*)(dst) = *(const uint4*)(o);
        *(uint4*)(dst + 8) = *(const uint4*)(o + 4);
    }
    {   // V: transpose via LDS
        const float* src = v + off;
#pragma unroll
        for (int j = 0; j < 16; j += 4) {
            float4 f = *(const float4*)(src + j);
            tile[cb + j + 0][r] = f2bf(f.x);
            tile[cb + j + 1][r] = f2bf(f.y);
            tile[cb + j + 2][r] = f2bf(f.z);
            tile[cb + j + 3][r] = f2bf(f.w);
        }
    }
    {   // W: fused fp32 -> bf16 convert (independent of the tile path)
        const int gid = blockIdx.x + 32 * (blockIdx.y + 16 * blockIdx.z);
        const int idx = gid * 256 + threadIdx.x;            // < E*E/2 = 524288
        float2 f = *(const float2*)(w + 2 * (size_t)idx);
        ((uint32_t*)wb)[idx] = pack_bf16(f.x, f.y);
    }
    __syncthreads();
    const int dv = threadIdx.x >> 2, seg = (threadIdx.x & 3) * 16;
    unsigned short* dst = vt + (((size_t)(b * H + h) * Dh + dv) * S + s0 + seg);
    *(uint4*)(dst) = *(const uint4*)(&tile[dv][seg]);
    *(uint4*)(dst + 8) = *(const uint4*)(&tile[dv][seg] + 8);
}

// ---------------- flash attention (R0 known-good structure) ----------------
// 64 q-rows per wave (256 q per block), 64-key double-buffered async-staged
// tiles. K/V fragments read from LDS ONCE per iter, reused by both q-halves.
// [R1: 32q/wave -> LDS-pipe saturated. R3: T15 pipeline -> scratch spill.
//  R7: setprio+cvt_pk -> -4%. R9: permlane exchange -> absmax fail.
//  This plain form is the measured best; do not touch.]
constexpr int GSTR = 528;   // 8-row group stride in shorts
__global__ __launch_bounds__(256, 2) void attn_kernel(const float* __restrict__ q,
                                                      const unsigned short* __restrict__ kb,
                                                      const unsigned short* __restrict__ vt,
                                                      unsigned short* __restrict__ attn) {
    __shared__ unsigned short smem[18432];   // 36 KB: 2 x (K 4224 + V 4224); epilogue 4x64x72

    // XCD swizzle: the 8 q-blocks of one (b,h) share an XCD's L2
    const int wid = blockIdx.x + 8 * (blockIdx.y + 16 * blockIdx.z);
    const int c_ = wid & 7, j_ = wid >> 3;
    const int bh = c_ * 8 + (j_ >> 3), qblk = j_ & 7;
    const int b = bh >> 4, h = bh & 15;

    const int tid = threadIdx.x;
    const int wave = tid >> 6, lane = tid & 63;
    const int l32 = lane & 31, half = lane >> 5;
    const int x7 = l32 & 7, y4 = l32 >> 3;

    const int q0 = qblk * 256 + wave * 64;
    const float scl = 0.125f * 1.44269504088896f;   // D^-0.5 * log2(e)

    // Q in registers: qreg[qh][t][j] = Q[q = q0+qh*32+l32][d = 16t + half*8 + j]
    bf16x8 qreg[2][4];
#pragma unroll
    for (int qh = 0; qh < 2; ++qh) {
        const float* qsrc = q + ((size_t)(b * S + q0 + qh * 32 + l32)) * E + h * Dh + half * 8;
#pragma unroll
        for (int t = 0; t < 4; ++t) {
            float4 f0 = *(const float4*)(qsrc + 16 * t);
            float4 f1 = *(const float4*)(qsrc + 16 * t + 4);
            bf16x8 r;
            r[0] = (short)f2bf(f0.x * scl); r[1] = (short)f2bf(f0.y * scl);
            r[2] = (short)f2bf(f0.z * scl); r[3] = (short)f2bf(f0.w * scl);
            r[4] = (short)f2bf(f1.x * scl); r[5] = (short)f2bf(f1.y * scl);
            r[6] = (short)f2bf(f1.z * scl); r[7] = (short)f2bf(f1.w * scl);
            qreg[qh][t] = r;
        }
    }

    f32x16 fzero;
#pragma unroll
    for (int r = 0; r < 16; ++r) fzero[r] = 0.f;
    f32x16 oacc[2][2];
#pragma unroll
    for (int qh = 0; qh < 2; ++qh)
#pragma unroll
        for (int mt = 0; mt < 2; ++mt) oacc[qh][mt] = fzero;
    float lsum[2] = {0.f, 0.f};

    // staging: one gload16 covers 8 rows x 128 B; lane -> (row8 = lane>>3,
    // slot = lane&7); fetch granule sg = slot ^ row8
    const int row8 = lane >> 3;
    const int sg = (lane & 7) ^ row8;
    const unsigned short* kbase = kb + ((size_t)(b * S)) * E + h * Dh;
    const unsigned short* vtb = vt + ((size_t)(b * H + h) * Dh) * S;

    auto stage = [&](int kt, int bsel) {
        unsigned short* ksb = smem + bsel * 8448;
        unsigned short* vsb = ksb + 4224;
#pragma unroll
        for (int u = 0; u < 2; ++u) {
            const int gi = wave * 2 + u;
            gload16(kbase + (size_t)(kt * 64 + gi * 8 + row8) * E + sg * 8, ksb + gi * GSTR);
            gload16(vtb + (size_t)(gi * 8 + row8) * S + kt * 64 + sg * 8, vsb + gi * GSTR);
        }
    };

    // per-lane row offsets for fragment reads (row r = mt*32 + l32)
    int roff[2];
#pragma unroll
    for (int mt = 0; mt < 2; ++mt) roff[mt] = (mt * 4 + y4) * GSTR + x7 * 64;

    constexpr int NT = S / 64;   // 32
    stage(0, 0);

    for (int kt = 0; kt < NT; ++kt) {
        const int cur = kt & 1;
        __syncthreads();   // drains tile-kt loads (in flight one full iteration)
        if (kt + 1 < NT) stage(kt + 1, cur ^ 1);
        const unsigned short* ksb = smem + cur * 8448;
        const unsigned short* vsb = ksb + 4224;

        // K fragments once per iter (shared by both q-halves)
        bf16x8 kfrag[2][4];
#pragma unroll
        for (int mt = 0; mt < 2; ++mt)
#pragma unroll
            for (int t = 0; t < 4; ++t)
                kfrag[mt][t] = *(const bf16x8*)(ksb + roff[mt] + (((t * 2 + half) ^ x7) * 8));

        // S^T[key][q] both q-halves
        f32x16 st[2][2];
#pragma unroll
        for (int qh = 0; qh < 2; ++qh)
#pragma unroll
            for (int mt = 0; mt < 2; ++mt) {
                st[qh][mt] = MFMA32(kfrag[mt][0], qreg[qh][0], fzero);
#pragma unroll
                for (int t = 1; t < 4; ++t)
                    st[qh][mt] = MFMA32(kfrag[mt][t], qreg[qh][t], st[qh][mt]);
            }

        // p = exp2(s); pack key-pairs. reg r of tile mt: key = (r&3)+8*(r>>2)+4*half+32*mt
        uint32_t pkd[2][2][4][2];
#pragma unroll
        for (int qh = 0; qh < 2; ++qh) {
            float ls = 0.f;
#pragma unroll
            for (int mt = 0; mt < 2; ++mt)
#pragma unroll
                for (int g = 0; g < 4; ++g) {
                    float p0 = exp2_fast(st[qh][mt][4 * g + 0]);
                    float p1 = exp2_fast(st[qh][mt][4 * g + 1]);
                    float p2 = exp2_fast(st[qh][mt][4 * g + 2]);
                    float p3 = exp2_fast(st[qh][mt][4 * g + 3]);
                    ls += (p0 + p1) + (p2 + p3);
                    pkd[qh][mt][g][0] = pack_bf16(p0, p1);
                    pkd[qh][mt][g][1] = pack_bf16(p2, p3);
                }
            lsum[qh] += ls;
        }

        // V^T fragments once per iter
        bf16x8 vfrag[2][4];
#pragma unroll
        for (int mt = 0; mt < 2; ++mt)
#pragma unroll
            for (int c = 0; c < 4; ++c)
                vfrag[mt][c] = *(const bf16x8*)(vsb + roff[mt] + (((c * 2 + half) ^ x7) * 8));

        // O^T += V^T · P^T
#pragma unroll
        for (int qh = 0; qh < 2; ++qh)
#pragma unroll
            for (int c = 0; c < 4; ++c) {
                const int ms = c >> 1;
                const int g0 = 2 * (c & 1);
                uint32_t a0 = pkd[qh][ms][g0][0], a1 = pkd[qh][ms][g0][1];
                uint32_t b0 = pkd[qh][ms][g0 + 1][0], b1 = pkd[qh][ms][g0 + 1][1];
                uint32_t snd0 = half ? a0 : b0;
                uint32_t snd1 = half ? a1 : b1;
                uint32_t r0 = (uint32_t)__shfl_xor((int)snd0, 32);
                uint32_t r1 = (uint32_t)__shfl_xor((int)snd1, 32);
                int4 bi;
                bi.x = (int)(half ? r0 : a0);
                bi.y = (int)(half ? r1 : a1);
                bi.z = (int)(half ? b0 : r0);
                bi.w = (int)(half ? b1 : r1);
                bf16x8 bfrag = __builtin_bit_cast(bf16x8, bi);
#pragma unroll
                for (int mt = 0; mt < 2; ++mt)
                    oacc[qh][mt] = MFMA32(vfrag[mt][c], bfrag, oacc[qh][mt]);
            }
    }

    // row sums across key-halves, normalize, transpose via LDS, store
    __syncthreads();   // all LDS reads done before smem reuse
    float inv[2];
#pragma unroll
    for (int qh = 0; qh < 2; ++qh) {
        float l = lsum[qh] + (float)__shfl_xor(lsum[qh], 32);
        inv[qh] = 1.0f / l;
    }

    unsigned short* ob = smem + wave * (64 * 72);   // [qrow 0..63][dv 0..63] stride 72
#pragma unroll
    for (int qh = 0; qh < 2; ++qh)
#pragma unroll
        for (int mt = 0; mt < 2; ++mt)
#pragma unroll
            for (int g = 0; g < 4; ++g) {
                int dv0 = 8 * g + 4 * half + 32 * mt;
                uint2 w2;
                w2.x = pack_bf16(oacc[qh][mt][4 * g + 0] * inv[qh],
                                 oacc[qh][mt][4 * g + 1] * inv[qh]);
                w2.y = pack_bf16(oacc[qh][mt][4 * g + 2] * inv[qh],
                                 oacc[qh][mt][4 * g + 3] * inv[qh]);
                *(uint2*)(ob + (qh * 32 + l32) * 72 + dv0) = w2;
            }
    __syncthreads();
#pragma unroll
    for (int it = 0; it < 2; ++it) {
        int row = it * 32 + (lane >> 1);
        int seg = (lane & 1) * 32;
        unsigned short* gdst = attn + ((size_t)(b * S + q0 + row)) * E + h * Dh + seg;
#pragma unroll
        for (int j = 0; j < 4; ++j) {
            bf16x8 v8 = *(const bf16x8*)(ob + row * 72 + seg + j * 8);
            *(bf16x8*)(gdst + j * 8) = v8;
        }
    }
}

// ---------------- projection GEMM: C = A @ W^T + bias ----------------
// M=8192, N=1024, K=1024. BM=BN=128, NEW BK=64 (was 32): halves the
// per-block barrier+vmcnt(0) drains 32->16 and doubles MFMA per phase
// 16->32 (m233: 2-phase critical path = stage+drain+barrier). LDS cost is
// free: grid=512 pins 2 blocks/CU; 2 x 33 KB x 2 tiles = 132 KB < 160 KB.
// Row stride is now 128 B (32 banks) so linear reads would 16-way conflict:
// apply the attn-kernel's verified rule-21 XOR pair -- pre-swizzled global
// source (sg = slot^row8), LINEAR gload_lds dest, XOR on read
// (chunk ^ (row&7)), 528-short group stride (same constants as attn).
constexpr int PGSTR = 528;   // 8-row group stride in shorts (8 rows x 64 + 16 pad)
__global__ __launch_bounds__(256) void proj_kernel(const unsigned short* __restrict__ A,
                                                   const unsigned short* __restrict__ W,
                                                   const float* __restrict__ bias,
                                                   float* __restrict__ C) {
    // 2 buffers x (A-tile 8448 + B-tile 8448) shorts = 66 KB
    __shared__ unsigned short smem[33792];
    const int tid = threadIdx.x;
    const int wave = tid >> 6, lane = tid & 63, quad = lane >> 4, l16 = lane & 15;
    const int wm = wave >> 1, wn = wave & 1;
    const int m0 = blockIdx.x * 128, n0 = blockIdx.y * 128;

    f32x4 acc[4][4];
    f32x4 zero = {0.f, 0.f, 0.f, 0.f};
#pragma unroll
    for (int mi = 0; mi < 4; ++mi)
#pragma unroll
        for (int ni = 0; ni < 4; ++ni) acc[mi][ni] = zero;

    // staging: one gload16 covers 8 rows x 128 B (one row = 64 shorts);
    // lane -> (row8 = lane>>3, slot = lane&7); fetch granule sg = slot^row8
    // so LDS slot s of row r holds global chunk s^(r&7) (attn-identical).
    const int row8 = lane >> 3;
    const int sg = (lane & 7) ^ row8;
    const unsigned short* Abase = A + (size_t)m0 * 1024;
    const unsigned short* Wbase = W + (size_t)n0 * 1024;

    auto stage = [&](int k0, int bsel) {
        unsigned short* as = smem + bsel * 16896;
        unsigned short* bs = as + 8448;
#pragma unroll
        for (int i = 0; i < 4; ++i) {
            const int g = wave * 4 + i;                 // 8-row group 0..15
            gload16(Abase + (size_t)(g * 8 + row8) * 1024 + k0 + sg * 8, as + g * PGSTR);
            gload16(Wbase + (size_t)(g * 8 + row8) * 1024 + k0 + sg * 8, bs + g * PGSTR);
        }
    };

    // per-lane row offsets for fragment reads: row r = (wm|wn)*64 + mi*16 + l16
    // addr = (r>>3)*PGSTR + (r&7)*64 + ((chunk ^ (r&7))*8), chunk = kk*4+quad
    const int x7p = l16 & 7;
    int aoff[4], boff[4];
#pragma unroll
    for (int mi = 0; mi < 4; ++mi) {
        const int ra = wm * 64 + mi * 16 + l16;
        aoff[mi] = (ra >> 3) * PGSTR + (ra & 7) * 64;
        const int rb = wn * 64 + mi * 16 + l16;
        boff[mi] = (rb >> 3) * PGSTR + (rb & 7) * 64;
    }

    constexpr int NT = 1024 / 64;   // 16
    stage(0, 0);

    for (int t = 0; t < NT; ++t) {
        const int cur = t & 1;
        __syncthreads();   // drains stage(t) (issued one full iteration ago)
        if (t + 1 < NT) stage((t + 1) * 64, cur ^ 1);
        const unsigned short* as = smem + cur * 16896;
        const unsigned short* bs = as + 8448;

        bf16x8 af[2][4], bfr[2][4];
#pragma unroll
        for (int kk = 0; kk < 2; ++kk)
#pragma unroll
            for (int mi = 0; mi < 4; ++mi) {
                af[kk][mi] = *(const bf16x8*)(as + aoff[mi] + (((kk * 4 + quad) ^ x7p) * 8));
                bfr[kk][mi] = *(const bf16x8*)(bs + boff[mi] + (((kk * 4 + quad) ^ x7p) * 8));
            }
#pragma unroll
        for (int kk = 0; kk < 2; ++kk)
#pragma unroll
            for (int mi = 0; mi < 4; ++mi)
#pragma unroll
                for (int ni = 0; ni < 4; ++ni)
                    acc[mi][ni] = MFMA16(af[kk][mi], bfr[kk][ni], acc[mi][ni]);
    }

    float bb[4];
#pragma unroll
    for (int ni = 0; ni < 4; ++ni) bb[ni] = bias[n0 + wn * 64 + ni * 16 + l16];
#pragma unroll
    for (int mi = 0; mi < 4; ++mi) {
        const int row = m0 + wm * 64 + mi * 16 + quad * 4;
#pragma unroll
        for (int ni = 0; ni < 4; ++ni) {
            const int col = n0 + wn * 64 + ni * 16 + l16;
#pragma unroll
            for (int r = 0; r < 4; ++r)
                C[(size_t)(row + r) * 1024 + col] = acc[mi][ni][r] + bb[ni];
        }
    }
}

extern "C" void kernel_launch(void* const* d_in, const int* in_sizes, int n_in,
                              void* d_out, int out_size, void* d_ws, size_t ws_size,
                              hipStream_t stream) {
    const float* q = (const float*)d_in[0];
    const float* k = (const float*)d_in[1];
    const float* v = (const float*)d_in[2];
    const float* w = (const float*)d_in[3];
    const float* bias = (const float*)d_in[4];
    float* out = (float*)d_out;

    unsigned short* ws = (unsigned short*)d_ws;
    unsigned short* kb = ws;                       // BSE bf16
    unsigned short* vt = kb + BSE;                 // BSE bf16, layout [B,H,Dh,S]
    unsigned short* attnb = vt + BSE;              // BSE bf16
    unsigned short* wb = attnb + BSE;              // E*E bf16

    prep_kv<<<dim3(S / 64, H, Bz), dim3(256), 0, stream>>>(k, v, w, kb, vt, wb);
    attn_kernel<<<dim3(S / 256, H, Bz), dim3(256), 0, stream>>>(q, kb, vt, attnb);
    proj_kernel<<<dim3((Bz * S) / 128, E / 128), dim3(256), 0, stream>>>(attnb, wb, bias, out);
}